// Round 1
// baseline (154.691 us; speedup 1.0000x reference)
//
#include <hip/hip_runtime.h>
#include <hip/hip_bf16.h>
#include <stdint.h>
#include <math.h>

#define B_N 128
#define D_N 512
#define H_N 1024
#define C_N 1000
#define CP  1024   // padded row stride for logits/g

// ---------------------------------------------------------------------------
// threefry2x32 (JAX-compatible, 20 rounds)
// ---------------------------------------------------------------------------
__device__ __forceinline__ uint32_t rotl32(uint32_t v, int r) {
  return (v << r) | (v >> (32 - r));
}

__device__ __forceinline__ void threefry2x32(uint32_t k0, uint32_t k1,
                                             uint32_t x0, uint32_t x1,
                                             uint32_t &o0, uint32_t &o1) {
  uint32_t ks2 = k0 ^ k1 ^ 0x1BD11BDAu;
#define TF_R(r) { x0 += x1; x1 = rotl32(x1, r); x1 ^= x0; }
  x0 += k0; x1 += k1;
  TF_R(13) TF_R(15) TF_R(26) TF_R(6)
  x0 += k1; x1 += ks2 + 1u;
  TF_R(17) TF_R(29) TF_R(16) TF_R(24)
  x0 += ks2; x1 += k0 + 2u;
  TF_R(13) TF_R(15) TF_R(26) TF_R(6)
  x0 += k0; x1 += k1 + 3u;
  TF_R(17) TF_R(29) TF_R(16) TF_R(24)
  x0 += k1; x1 += ks2 + 4u;
  TF_R(13) TF_R(15) TF_R(26) TF_R(6)
  x0 += ks2; x1 += k0 + 5u;
#undef TF_R
  o0 = x0; o1 = x1;
}

// partitionable-mode 32-bit random bits -> gumbel sample for position i
__device__ __forceinline__ float gumbel_from_key(uint32_t k0, uint32_t k1, uint32_t i) {
  uint32_t o0, o1;
  threefry2x32(k0, k1, 0u, i, o0, o1);
  uint32_t bits = o0 ^ o1;
  uint32_t fb = (bits >> 9) | 0x3f800000u;
  float f = __uint_as_float(fb) - 1.0f;            // [0, 1)
  const float tiny = 1.1754943508222875e-38f;
  float u = fmaxf(tiny, f * (1.0f - tiny) + tiny); // JAX uniform(minval=tiny)
  return -logf(-logf(u));
}

// ---------------------------------------------------------------------------
// block reductions (512 threads = 8 waves)
// ---------------------------------------------------------------------------
__device__ __forceinline__ float block_sum512(float v, float* red) {
  #pragma unroll
  for (int o = 32; o; o >>= 1) v += __shfl_xor(v, o);
  __syncthreads();
  if ((threadIdx.x & 63) == 0) red[threadIdx.x >> 6] = v;
  __syncthreads();
  return red[0] + red[1] + red[2] + red[3] + red[4] + red[5] + red[6] + red[7];
}

__device__ __forceinline__ float block_max512(float v, float* red) {
  #pragma unroll
  for (int o = 32; o; o >>= 1) v = fmaxf(v, __shfl_xor(v, o));
  __syncthreads();
  if ((threadIdx.x & 63) == 0) red[threadIdx.x >> 6] = v;
  __syncthreads();
  float m = red[0];
  #pragma unroll
  for (int w = 1; w < 8; w++) m = fmaxf(m, red[w]);
  return m;
}

// ---------------------------------------------------------------------------
// K0: W2 [H][C] -> W2T [C][H] (row stride H_N), coalesced both sides
// ---------------------------------------------------------------------------
__global__ __launch_bounds__(256) void k_transpose(const float* __restrict__ W2,
                                                   float* __restrict__ W2T) {
  __shared__ float tile[32][33];
  int c0 = blockIdx.x * 32;
  int j0 = blockIdx.y * 32;
  int tx = threadIdx.x & 31;
  int ty = threadIdx.x >> 5;   // 0..7
  #pragma unroll
  for (int r = 0; r < 4; r++) {
    int j = j0 + ty + r * 8;   // < 1024 always
    int c = c0 + tx;
    tile[ty + r * 8][tx] = (c < C_N) ? W2[j * C_N + c] : 0.0f;
  }
  __syncthreads();
  #pragma unroll
  for (int r = 0; r < 4; r++) {
    int c = c0 + ty + r * 8;
    int j = j0 + tx;
    if (c < C_N) W2T[c * H_N + j] = tile[tx][ty + r * 8];
  }
}

// ---------------------------------------------------------------------------
// K1: hpre[128][1024] = X @ W1 + b1.  Block: 16 samples x 128 cols.
// ---------------------------------------------------------------------------
__global__ __launch_bounds__(512) void k_fc1(const float* __restrict__ X,
                                             const float* __restrict__ W1,
                                             const float* __restrict__ b1,
                                             float* __restrict__ hpre) {
  __shared__ float xs[16 * D_N];  // 32 KB
  int cbase = blockIdx.x * 128;
  int sbase = blockIdx.y * 16;
  int t = threadIdx.x;
  #pragma unroll
  for (int k = 0; k < 16; k++) {
    int idx = t + k * 512;            // 0..8191
    int s = idx >> 9, d = idx & 511;
    xs[idx] = X[(sbase + s) * D_N + d];
  }
  __syncthreads();
  int c = cbase + (t & 127);
  int sq = t >> 7;                    // 0..3 -> 4 samples each
  float acc0 = 0, acc1 = 0, acc2 = 0, acc3 = 0;
  const float* xp = &xs[(sq * 4) * D_N];
  for (int d = 0; d < D_N; d += 4) {
    float w0 = W1[(d + 0) * H_N + c];
    float w1 = W1[(d + 1) * H_N + c];
    float w2 = W1[(d + 2) * H_N + c];
    float w3 = W1[(d + 3) * H_N + c];
    float4 xA = *reinterpret_cast<const float4*>(&xp[0 * D_N + d]);
    float4 xB = *reinterpret_cast<const float4*>(&xp[1 * D_N + d]);
    float4 xC = *reinterpret_cast<const float4*>(&xp[2 * D_N + d]);
    float4 xD = *reinterpret_cast<const float4*>(&xp[3 * D_N + d]);
    acc0 += xA.x * w0 + xA.y * w1 + xA.z * w2 + xA.w * w3;
    acc1 += xB.x * w0 + xB.y * w1 + xB.z * w2 + xB.w * w3;
    acc2 += xC.x * w0 + xC.y * w1 + xC.z * w2 + xC.w * w3;
    acc3 += xD.x * w0 + xD.y * w1 + xD.z * w2 + xD.w * w3;
  }
  float bb = b1[c];
  int srow = sbase + sq * 4;
  hpre[(srow + 0) * H_N + c] = acc0 + bb;
  hpre[(srow + 1) * H_N + c] = acc1 + bb;
  hpre[(srow + 2) * H_N + c] = acc2 + bb;
  hpre[(srow + 3) * H_N + c] = acc3 + bb;
}

// ---------------------------------------------------------------------------
// K2: logits[128][CP] = relu(hpre) @ W2 + b2.  Block: 16 samples x 128 cols.
// ---------------------------------------------------------------------------
__global__ __launch_bounds__(512) void k_fc2(const float* __restrict__ hpre,
                                             const float* __restrict__ W2,
                                             const float* __restrict__ b2,
                                             float* __restrict__ logits) {
  __shared__ float hs[16 * H_N];  // 64 KB
  int cbase = blockIdx.x * 128;
  int sbase = blockIdx.y * 16;
  int t = threadIdx.x;
  #pragma unroll
  for (int k = 0; k < 32; k++) {
    int idx = t + k * 512;            // 0..16383
    int s = idx >> 10, j = idx & 1023;
    hs[idx] = fmaxf(hpre[(sbase + s) * H_N + j], 0.0f);
  }
  __syncthreads();
  int c = cbase + (t & 127);
  int sq = t >> 7;
  if (c < C_N) {
    float acc0 = 0, acc1 = 0, acc2 = 0, acc3 = 0;
    const float* hp = &hs[(sq * 4) * H_N];
    for (int j = 0; j < H_N; j += 4) {
      float w0 = W2[(j + 0) * C_N + c];
      float w1 = W2[(j + 1) * C_N + c];
      float w2 = W2[(j + 2) * C_N + c];
      float w3 = W2[(j + 3) * C_N + c];
      float4 hA = *reinterpret_cast<const float4*>(&hp[0 * H_N + j]);
      float4 hB = *reinterpret_cast<const float4*>(&hp[1 * H_N + j]);
      float4 hC = *reinterpret_cast<const float4*>(&hp[2 * H_N + j]);
      float4 hD = *reinterpret_cast<const float4*>(&hp[3 * H_N + j]);
      acc0 += hA.x * w0 + hA.y * w1 + hA.z * w2 + hA.w * w3;
      acc1 += hB.x * w0 + hB.y * w1 + hB.z * w2 + hB.w * w3;
      acc2 += hC.x * w0 + hC.y * w1 + hC.z * w2 + hC.w * w3;
      acc3 += hD.x * w0 + hD.y * w1 + hD.z * w2 + hD.w * w3;
    }
    float bb = b2[c];
    int srow = sbase + sq * 4;
    logits[(srow + 0) * CP + c] = acc0 + bb;
    logits[(srow + 1) * CP + c] = acc1 + bb;
    logits[(srow + 2) * CP + c] = acc2 + bb;
    logits[(srow + 3) * CP + c] = acc3 + bb;
  }
}

// ---------------------------------------------------------------------------
// K3: per-sample categorical sampling + softmax grad g, norms, W2/b2 traces.
// One block (512 thr) per sample.
// ---------------------------------------------------------------------------
__global__ __launch_bounds__(512) void k_sample(const float* __restrict__ X,
                                                const float* __restrict__ hpre,
                                                const float* __restrict__ logits,
                                                float* __restrict__ g,
                                                float* __restrict__ xsq_out,
                                                float* __restrict__ acc) {
  __shared__ float lg[C_N];
  __shared__ float red[8];
  __shared__ float redv[8];
  __shared__ int   redi[8];
  __shared__ uint32_t keys[2];
  int b = blockIdx.x;
  int t = threadIdx.x;

  lg[t] = logits[b * CP + t];                       // t < 512 < 1000
  if (t + 512 < C_N) lg[t + 512] = logits[b * CP + t + 512];
  if (t == 0) {
    // fold-like split: key_b = threefry(key(42)=(0,42), (0, b))
    uint32_t o0, o1;
    threefry2x32(0u, 42u, 0u, (uint32_t)b, o0, o1);
    keys[0] = o0; keys[1] = o1;
  }
  __syncthreads();
  uint32_t k0 = keys[0], k1 = keys[1];

  // gumbel-argmax over 1000 classes (positions t and t+512)
  float bz = -INFINITY; int bi = 0x7fffffff;
  {
    float z0 = lg[t] + gumbel_from_key(k0, k1, (uint32_t)t);
    bz = z0; bi = t;
    if (t + 512 < C_N) {
      float z1 = lg[t + 512] + gumbel_from_key(k0, k1, (uint32_t)(t + 512));
      if (z1 > bz || (z1 == bz && (t + 512) < bi)) { bz = z1; bi = t + 512; }
    }
  }
  #pragma unroll
  for (int o = 32; o; o >>= 1) {
    float ov = __shfl_xor(bz, o);
    int   oi = __shfl_xor(bi, o);
    if (ov > bz || (ov == bz && oi < bi)) { bz = ov; bi = oi; }
  }
  if ((t & 63) == 0) { redv[t >> 6] = bz; redi[t >> 6] = bi; }
  __syncthreads();
  if (t == 0) {
    #pragma unroll
    for (int w = 1; w < 8; w++) {
      if (redv[w] > redv[0] || (redv[w] == redv[0] && redi[w] < redi[0])) {
        redv[0] = redv[w]; redi[0] = redi[w];
      }
    }
  }
  __syncthreads();
  int y = redi[0];

  // softmax
  float lm = lg[t];
  if (t + 512 < C_N) lm = fmaxf(lm, lg[t + 512]);
  float m = block_max512(lm, red);
  float e0 = __expf(0.0f); // placeholder to keep compiler honest (unused)
  (void)e0;
  float ea = expf(lg[t] - m);
  float eb = (t + 512 < C_N) ? expf(lg[t + 512] - m) : 0.0f;
  float sum1 = block_sum512(ea + eb, red);
  float inv = 1.0f / sum1;

  float ga = ea * inv - ((t == y) ? 1.0f : 0.0f);
  float gb2 = eb * inv - (((t + 512) == y) ? 1.0f : 0.0f);
  g[b * CP + t] = ga;
  if (t + 512 < C_N) g[b * CP + t + 512] = gb2;
  float gn = ga * ga + ((t + 512 < C_N) ? gb2 * gb2 : 0.0f);
  float tnorm = block_sum512(gn, red);   // ||g||^2

  // ||h||^2
  float h0 = fmaxf(hpre[b * H_N + t], 0.0f);
  float h1 = fmaxf(hpre[b * H_N + t + 512], 0.0f);
  float hsq = block_sum512(h0 * h0 + h1 * h1, red);

  // ||x||^2
  float xv = (t < D_N) ? X[b * D_N + t] : 0.0f;
  float xsq = block_sum512(xv * xv, red);

  if (t == 0) {
    xsq_out[b] = xsq;
    atomicAdd(&acc[2], hsq * tnorm);  // W2 trace numerator
    atomicAdd(&acc[3], tnorm);       // b2 trace numerator
  }
}

// ---------------------------------------------------------------------------
// K4: ghat = (g @ W2T) masked by hpre>0; accumulate b1 / W1 traces.
// Block: 16 samples x 128 j-cols.
// ---------------------------------------------------------------------------
__global__ __launch_bounds__(512) void k_bwd1(const float* __restrict__ g,
                                              const float* __restrict__ W2T,
                                              const float* __restrict__ hpre,
                                              const float* __restrict__ xsq,
                                              float* __restrict__ acc) {
  __shared__ float gs[16 * C_N];  // 64000 B
  __shared__ float red[8];
  int jbase = blockIdx.x * 128;
  int sbase = blockIdx.y * 16;
  int t = threadIdx.x;
  #pragma unroll
  for (int k = 0; k < 32; k++) {
    int idx = t + k * 512;
    if (idx < 16 * C_N) {
      int s = idx / C_N;
      int cc = idx - s * C_N;
      gs[idx] = g[(sbase + s) * CP + cc];
    }
  }
  __syncthreads();
  int j = jbase + (t & 127);
  int sq = t >> 7;
  float acc0 = 0, acc1 = 0, acc2 = 0, acc3 = 0;
  const float* gp = &gs[(sq * 4) * C_N];
  for (int c = 0; c < C_N; c += 4) {
    float w0 = W2T[(c + 0) * H_N + j];
    float w1 = W2T[(c + 1) * H_N + j];
    float w2 = W2T[(c + 2) * H_N + j];
    float w3 = W2T[(c + 3) * H_N + j];
    float4 gA = *reinterpret_cast<const float4*>(&gp[0 * C_N + c]);
    float4 gB = *reinterpret_cast<const float4*>(&gp[1 * C_N + c]);
    float4 gC = *reinterpret_cast<const float4*>(&gp[2 * C_N + c]);
    float4 gD = *reinterpret_cast<const float4*>(&gp[3 * C_N + c]);
    acc0 += gA.x * w0 + gA.y * w1 + gA.z * w2 + gA.w * w3;
    acc1 += gB.x * w0 + gB.y * w1 + gB.z * w2 + gB.w * w3;
    acc2 += gC.x * w0 + gC.y * w1 + gC.z * w2 + gC.w * w3;
    acc3 += gD.x * w0 + gD.y * w1 + gD.z * w2 + gD.w * w3;
  }
  float a4[4] = {acc0, acc1, acc2, acc3};
  float cb1 = 0, cw1 = 0;
  int srow = sbase + sq * 4;
  #pragma unroll
  for (int s4 = 0; s4 < 4; s4++) {
    float hp = hpre[(srow + s4) * H_N + j];
    float val = (hp > 0.0f) ? a4[s4] : 0.0f;
    float v2 = val * val;
    cb1 += v2;
    cw1 += xsq[srow + s4] * v2;
  }
  float tb1 = block_sum512(cb1, red);
  float tw1 = block_sum512(cw1, red);
  if (t == 0) {
    atomicAdd(&acc[1], tb1);  // b1
    atomicAdd(&acc[0], tw1);  // W1
  }
}

// ---------------------------------------------------------------------------
// K5: finalize output [overall, W1, b1, W2, b2]
// ---------------------------------------------------------------------------
__global__ void k_final(const float* __restrict__ acc, float* __restrict__ out) {
  if (threadIdx.x == 0) {
    float w1 = acc[0] / 128.0f;
    float b1 = acc[1] / 128.0f;
    float w2 = acc[2] / 128.0f;
    float b2 = acc[3] / 128.0f;
    out[0] = w1 + b1 + w2 + b2;
    out[1] = w1;
    out[2] = b1;
    out[3] = w2;
    out[4] = b2;
  }
}

// ---------------------------------------------------------------------------
extern "C" void kernel_launch(void* const* d_in, const int* in_sizes, int n_in,
                              void* d_out, int out_size, void* d_ws, size_t ws_size,
                              hipStream_t stream) {
  const float* X  = (const float*)d_in[0];
  const float* W1 = (const float*)d_in[1];
  const float* b1 = (const float*)d_in[2];
  const float* W2 = (const float*)d_in[3];
  const float* b2 = (const float*)d_in[4];
  float* out = (float*)d_out;

  float* ws     = (float*)d_ws;
  float* W2T    = ws;                       // 1,024,000 floats ([1000][1024])
  float* hpre   = ws + 1024000;             // 131072
  float* logits = hpre + 131072;            // 131072 (stride 1024)
  float* g      = logits + 131072;          // 131072 (stride 1024)
  float* xsq    = g + 131072;               // 128
  float* accb   = xsq + 128;                // 4

  hipMemsetAsync(accb, 0, 4 * sizeof(float), stream);
  k_transpose<<<dim3(32, 32), 256, 0, stream>>>(W2, W2T);
  k_fc1<<<dim3(8, 8), 512, 0, stream>>>(X, W1, b1, hpre);
  k_fc2<<<dim3(8, 8), 512, 0, stream>>>(hpre, W2, b2, logits);
  k_sample<<<B_N, 512, 0, stream>>>(X, hpre, logits, g, xsq, accb);
  k_bwd1<<<dim3(8, 8), 512, 0, stream>>>(g, W2T, hpre, xsq, accb);
  k_final<<<1, 64, 0, stream>>>(accb, out);
}

// Round 2
// 66.346 us; speedup vs baseline: 2.3316x; 2.3316x over previous
//
#include <hip/hip_runtime.h>
#include <hip/hip_bf16.h>
#include <stdint.h>
#include <math.h>

#define B_N 128
#define D_N 512
#define H_N 1024
#define C_N 1000
#define CP  1024   // padded row stride for logits/g

// ---------------------------------------------------------------------------
// threefry2x32 (JAX-compatible, 20 rounds) -- verified bit-exact (R1 absmax 0)
// ---------------------------------------------------------------------------
__device__ __forceinline__ uint32_t rotl32(uint32_t v, int r) {
  return (v << r) | (v >> (32 - r));
}

__device__ __forceinline__ void threefry2x32(uint32_t k0, uint32_t k1,
                                             uint32_t x0, uint32_t x1,
                                             uint32_t &o0, uint32_t &o1) {
  uint32_t ks2 = k0 ^ k1 ^ 0x1BD11BDAu;
#define TF_R(r) { x0 += x1; x1 = rotl32(x1, r); x1 ^= x0; }
  x0 += k0; x1 += k1;
  TF_R(13) TF_R(15) TF_R(26) TF_R(6)
  x0 += k1; x1 += ks2 + 1u;
  TF_R(17) TF_R(29) TF_R(16) TF_R(24)
  x0 += ks2; x1 += k0 + 2u;
  TF_R(13) TF_R(15) TF_R(26) TF_R(6)
  x0 += k0; x1 += k1 + 3u;
  TF_R(17) TF_R(29) TF_R(16) TF_R(24)
  x0 += k1; x1 += ks2 + 4u;
  TF_R(13) TF_R(15) TF_R(26) TF_R(6)
  x0 += ks2; x1 += k0 + 5u;
#undef TF_R
  o0 = x0; o1 = x1;
}

__device__ __forceinline__ float gumbel_from_key(uint32_t k0, uint32_t k1, uint32_t i) {
  uint32_t o0, o1;
  threefry2x32(k0, k1, 0u, i, o0, o1);
  uint32_t bits = o0 ^ o1;
  uint32_t fb = (bits >> 9) | 0x3f800000u;
  float f = __uint_as_float(fb) - 1.0f;            // [0, 1)
  const float tiny = 1.1754943508222875e-38f;
  float u = fmaxf(tiny, f * (1.0f - tiny) + tiny); // JAX uniform(minval=tiny)
  return -logf(-logf(u));
}

// ---------------------------------------------------------------------------
// block reductions (512 threads = 8 waves)
// ---------------------------------------------------------------------------
__device__ __forceinline__ float block_sum512(float v, float* red) {
  #pragma unroll
  for (int o = 32; o; o >>= 1) v += __shfl_xor(v, o);
  __syncthreads();
  if ((threadIdx.x & 63) == 0) red[threadIdx.x >> 6] = v;
  __syncthreads();
  return red[0] + red[1] + red[2] + red[3] + red[4] + red[5] + red[6] + red[7];
}

__device__ __forceinline__ float block_max512(float v, float* red) {
  #pragma unroll
  for (int o = 32; o; o >>= 1) v = fmaxf(v, __shfl_xor(v, o));
  __syncthreads();
  if ((threadIdx.x & 63) == 0) red[threadIdx.x >> 6] = v;
  __syncthreads();
  float m = red[0];
  #pragma unroll
  for (int w = 1; w < 8; w++) m = fmaxf(m, red[w]);
  return m;
}

// ---------------------------------------------------------------------------
// K1: hpre[128][1024] = X @ W1 + b1.
// grid (8, 32): c-tile 128, 4 samples/block; 256 thr, 2 samples/thread.
// 16 W1 loads batched per iter -> latency exposed once per 16 loads.
// ---------------------------------------------------------------------------
__global__ __launch_bounds__(256) void k_fc1(const float* __restrict__ X,
                                             const float* __restrict__ W1,
                                             const float* __restrict__ b1,
                                             float* __restrict__ hpre) {
  __shared__ float xs[4 * D_N];  // 8 KB
  int cbase = blockIdx.x * 128;
  int sbase = blockIdx.y * 4;
  int t = threadIdx.x;
  #pragma unroll
  for (int k = 0; k < 8; k++) {
    int idx = t + k * 256;            // 0..2047
    int s = idx >> 9, d = idx & 511;
    xs[idx] = X[(sbase + s) * D_N + d];
  }
  __syncthreads();
  int c = cbase + (t & 127);
  int sq = t >> 7;                    // 0,1
  const float* xp0 = &xs[(sq * 2 + 0) * D_N];
  const float* xp1 = &xs[(sq * 2 + 1) * D_N];
  float acc0 = 0.f, acc1 = 0.f;
  const float* W1c = W1 + c;
  for (int d0 = 0; d0 < D_N; d0 += 16) {
    float w[16];
    #pragma unroll
    for (int i = 0; i < 16; i++) w[i] = W1c[(d0 + i) * H_N];
    #pragma unroll
    for (int q = 0; q < 4; q++) {
      float4 xa = *reinterpret_cast<const float4*>(&xp0[d0 + q * 4]);
      float4 xb = *reinterpret_cast<const float4*>(&xp1[d0 + q * 4]);
      acc0 += xa.x * w[q*4+0] + xa.y * w[q*4+1] + xa.z * w[q*4+2] + xa.w * w[q*4+3];
      acc1 += xb.x * w[q*4+0] + xb.y * w[q*4+1] + xb.z * w[q*4+2] + xb.w * w[q*4+3];
    }
  }
  float bb = b1[c];
  int s0 = sbase + sq * 2;
  hpre[(s0 + 0) * H_N + c] = acc0 + bb;
  hpre[(s0 + 1) * H_N + c] = acc1 + bb;
}

// ---------------------------------------------------------------------------
// K2: logits_part[kb][128][CP] = relu(hpre[:, kb*512:+512]) @ W2[kb*512:+512,:]
// grid (8, 16, 2): c-tile 128, 8 samples/block, K-split 2; 256 thr.
// b2 and the part-sum are applied in k_sample.
// ---------------------------------------------------------------------------
__global__ __launch_bounds__(256) void k_fc2(const float* __restrict__ hpre,
                                             const float* __restrict__ W2,
                                             float* __restrict__ logits_part) {
  __shared__ float hs[8 * 512];  // 16 KB
  int cbase = blockIdx.x * 128;
  int sbase = blockIdx.y * 8;
  int kb = blockIdx.z;           // 0,1
  int t = threadIdx.x;
  #pragma unroll
  for (int k = 0; k < 16; k++) {
    int idx = t + k * 256;            // 0..4095
    int s = idx >> 9, j = idx & 511;
    hs[idx] = fmaxf(hpre[(sbase + s) * H_N + kb * 512 + j], 0.0f);
  }
  __syncthreads();
  int c = cbase + (t & 127);
  int sq = t >> 7;                    // 0,1 -> 4 samples each
  if (c < C_N) {
    const float* hp0 = &hs[(sq * 4 + 0) * 512];
    const float* hp1 = &hs[(sq * 4 + 1) * 512];
    const float* hp2 = &hs[(sq * 4 + 2) * 512];
    const float* hp3 = &hs[(sq * 4 + 3) * 512];
    float a0 = 0.f, a1 = 0.f, a2 = 0.f, a3 = 0.f;
    const float* W2c = W2 + (size_t)(kb * 512) * C_N + c;
    for (int j0 = 0; j0 < 512; j0 += 8) {
      float w[8];
      #pragma unroll
      for (int i = 0; i < 8; i++) w[i] = W2c[(j0 + i) * C_N];
      #pragma unroll
      for (int q = 0; q < 2; q++) {
        float4 hA = *reinterpret_cast<const float4*>(&hp0[j0 + q * 4]);
        float4 hB = *reinterpret_cast<const float4*>(&hp1[j0 + q * 4]);
        float4 hC = *reinterpret_cast<const float4*>(&hp2[j0 + q * 4]);
        float4 hD = *reinterpret_cast<const float4*>(&hp3[j0 + q * 4]);
        a0 += hA.x * w[q*4+0] + hA.y * w[q*4+1] + hA.z * w[q*4+2] + hA.w * w[q*4+3];
        a1 += hB.x * w[q*4+0] + hB.y * w[q*4+1] + hB.z * w[q*4+2] + hB.w * w[q*4+3];
        a2 += hC.x * w[q*4+0] + hC.y * w[q*4+1] + hC.z * w[q*4+2] + hC.w * w[q*4+3];
        a3 += hD.x * w[q*4+0] + hD.y * w[q*4+1] + hD.z * w[q*4+2] + hD.w * w[q*4+3];
      }
    }
    float* lp = logits_part + (size_t)kb * (B_N * CP);
    int s0 = sbase + sq * 4;
    lp[(s0 + 0) * CP + c] = a0;
    lp[(s0 + 1) * CP + c] = a1;
    lp[(s0 + 2) * CP + c] = a2;
    lp[(s0 + 3) * CP + c] = a3;
  }
}

// ---------------------------------------------------------------------------
// K3: per-sample categorical sampling + softmax grad g, norms, W2/b2 partials.
// One block (512 thr) per sample. Writes g zero-padded to CP cols.
// ---------------------------------------------------------------------------
__global__ __launch_bounds__(512) void k_sample(const float* __restrict__ X,
                                                const float* __restrict__ hpre,
                                                const float* __restrict__ logits_part,
                                                const float* __restrict__ b2,
                                                float* __restrict__ g,
                                                float* __restrict__ xsq_out,
                                                float* __restrict__ samp_part) {
  __shared__ float lg[C_N];
  __shared__ float red[8];
  __shared__ float redv[8];
  __shared__ int   redi[8];
  __shared__ uint32_t keys[2];
  int b = blockIdx.x;
  int t = threadIdx.x;

  const float* p0 = logits_part;
  const float* p1 = logits_part + (B_N * CP);
  lg[t] = p0[b * CP + t] + p1[b * CP + t] + b2[t];
  if (t + 512 < C_N)
    lg[t + 512] = p0[b * CP + t + 512] + p1[b * CP + t + 512] + b2[t + 512];
  if (t == 0) {
    uint32_t o0, o1;
    threefry2x32(0u, 42u, 0u, (uint32_t)b, o0, o1);
    keys[0] = o0; keys[1] = o1;
  }
  __syncthreads();
  uint32_t k0 = keys[0], k1 = keys[1];

  // gumbel-argmax over 1000 classes
  float bz = -INFINITY; int bi = 0x7fffffff;
  {
    float z0 = lg[t] + gumbel_from_key(k0, k1, (uint32_t)t);
    bz = z0; bi = t;
    if (t + 512 < C_N) {
      float z1 = lg[t + 512] + gumbel_from_key(k0, k1, (uint32_t)(t + 512));
      if (z1 > bz || (z1 == bz && (t + 512) < bi)) { bz = z1; bi = t + 512; }
    }
  }
  #pragma unroll
  for (int o = 32; o; o >>= 1) {
    float ov = __shfl_xor(bz, o);
    int   oi = __shfl_xor(bi, o);
    if (ov > bz || (ov == bz && oi < bi)) { bz = ov; bi = oi; }
  }
  if ((t & 63) == 0) { redv[t >> 6] = bz; redi[t >> 6] = bi; }
  __syncthreads();
  if (t == 0) {
    #pragma unroll
    for (int w = 1; w < 8; w++) {
      if (redv[w] > redv[0] || (redv[w] == redv[0] && redi[w] < redi[0])) {
        redv[0] = redv[w]; redi[0] = redi[w];
      }
    }
  }
  __syncthreads();
  int y = redi[0];

  // softmax
  float lm = lg[t];
  if (t + 512 < C_N) lm = fmaxf(lm, lg[t + 512]);
  float m = block_max512(lm, red);
  float ea = expf(lg[t] - m);
  float eb = (t + 512 < C_N) ? expf(lg[t + 512] - m) : 0.0f;
  float sum1 = block_sum512(ea + eb, red);
  float inv = 1.0f / sum1;

  float ga  = ea * inv - ((t == y) ? 1.0f : 0.0f);
  float gb2 = eb * inv - (((t + 512) == y) ? 1.0f : 0.0f);
  g[b * CP + t] = ga;
  g[b * CP + t + 512] = (t + 512 < C_N) ? gb2 : 0.0f;  // zero-pad cols 1000..1023
  float gn = ga * ga + ((t + 512 < C_N) ? gb2 * gb2 : 0.0f);
  float tnorm = block_sum512(gn, red);   // ||g||^2

  // ||h||^2
  float h0 = fmaxf(hpre[b * H_N + t], 0.0f);
  float h1 = fmaxf(hpre[b * H_N + t + 512], 0.0f);
  float hsq = block_sum512(h0 * h0 + h1 * h1, red);

  // ||x||^2
  float xv = (t < D_N) ? X[b * D_N + t] : 0.0f;
  float xsq = block_sum512(xv * xv, red);

  if (t == 0) {
    xsq_out[b] = xsq;
    samp_part[b * 2 + 0] = hsq * tnorm;  // W2 trace numerator
    samp_part[b * 2 + 1] = tnorm;        // b2 trace numerator
  }
}

// ---------------------------------------------------------------------------
// K4: wave-dot ghat = g . W2-rows (contiguous c axis, no transpose needed),
// fused mask/square/trace. grid (64, 16) = 1024 blocks, 512 thr.
// Wave w owns j = jb + 2w + {0,1}, all 8 staged samples. Lanes over c.
// ---------------------------------------------------------------------------
__global__ __launch_bounds__(512) void k_bwd1(const float* __restrict__ g,
                                              const float* __restrict__ W2,
                                              const float* __restrict__ hpre,
                                              const float* __restrict__ xsq,
                                              float* __restrict__ bwd_part) {
  __shared__ float gs[8 * 1024];  // 32 KB, zero-padded cols from k_sample
  __shared__ float xq[8];
  __shared__ float wred[8][2];
  int jb = blockIdx.x * 16;
  int sbase = blockIdx.y * 8;
  int t = threadIdx.x;
  #pragma unroll
  for (int k = 0; k < 16; k++) {
    int idx = t + k * 512;            // 0..8191
    gs[idx] = g[(sbase + (idx >> 10)) * CP + (idx & 1023)];
  }
  if (t < 8) xq[t] = xsq[sbase + t];
  __syncthreads();

  int w = t >> 6, lane = t & 63;
  int j0 = jb + w * 2, j1 = j0 + 1;
  float a0[8] = {0,0,0,0,0,0,0,0};
  float a1[8] = {0,0,0,0,0,0,0,0};
  const float* w2r0 = W2 + (size_t)j0 * C_N;
  const float* w2r1 = W2 + (size_t)j1 * C_N;
  #pragma unroll
  for (int it = 0; it < 4; it++) {
    int c0 = it * 256 + lane * 4;
    bool act = (c0 < C_N);            // only the it==3 tail can be inactive
    float4 wv0 = act ? *reinterpret_cast<const float4*>(w2r0 + c0)
                     : make_float4(0.f, 0.f, 0.f, 0.f);
    float4 wv1 = act ? *reinterpret_cast<const float4*>(w2r1 + c0)
                     : make_float4(0.f, 0.f, 0.f, 0.f);
    #pragma unroll
    for (int s = 0; s < 8; s++) {
      float4 gv = *reinterpret_cast<const float4*>(&gs[s * 1024 + c0]);
      a0[s] += wv0.x * gv.x + wv0.y * gv.y + wv0.z * gv.z + wv0.w * gv.w;
      a1[s] += wv1.x * gv.x + wv1.y * gv.y + wv1.z * gv.z + wv1.w * gv.w;
    }
  }
  #pragma unroll
  for (int off = 32; off; off >>= 1) {
    #pragma unroll
    for (int s = 0; s < 8; s++) {
      a0[s] += __shfl_xor(a0[s], off);
      a1[s] += __shfl_xor(a1[s], off);
    }
  }
  // all lanes now hold the full dots; epilogue is lane-uniform
  float cb = 0.f, cw = 0.f;
  #pragma unroll
  for (int s = 0; s < 8; s++) {
    float h0 = hpre[(sbase + s) * H_N + j0];
    float h1 = hpre[(sbase + s) * H_N + j1];
    float v0 = (h0 > 0.f) ? a0[s] : 0.f;
    float v1 = (h1 > 0.f) ? a1[s] : 0.f;
    float q = v0 * v0 + v1 * v1;
    cb += q;
    cw += xq[s] * q;
  }
  if (lane == 0) { wred[w][0] = cw; wred[w][1] = cb; }
  __syncthreads();
  if (t == 0) {
    float sw = 0.f, sb = 0.f;
    #pragma unroll
    for (int i = 0; i < 8; i++) { sw += wred[i][0]; sb += wred[i][1]; }
    int bid = blockIdx.y * 64 + blockIdx.x;
    bwd_part[bid * 2 + 0] = sw;   // W1 trace partial
    bwd_part[bid * 2 + 1] = sb;   // b1 trace partial
  }
}

// ---------------------------------------------------------------------------
// K5: deterministic final reduction of all partials -> out[5]
// ---------------------------------------------------------------------------
__global__ __launch_bounds__(512) void k_final(const float* __restrict__ samp_part,
                                               const float* __restrict__ bwd_part,
                                               float* __restrict__ out) {
  __shared__ float red[8];
  int t = threadIdx.x;
  float w1v = bwd_part[t * 2 + 0] + bwd_part[(t + 512) * 2 + 0];
  float b1v = bwd_part[t * 2 + 1] + bwd_part[(t + 512) * 2 + 1];
  float w2v = (t < B_N) ? samp_part[t * 2 + 0] : 0.f;
  float b2v = (t < B_N) ? samp_part[t * 2 + 1] : 0.f;
  w1v = block_sum512(w1v, red);
  b1v = block_sum512(b1v, red);
  w2v = block_sum512(w2v, red);
  b2v = block_sum512(b2v, red);
  if (t == 0) {
    w1v /= 128.0f; b1v /= 128.0f; w2v /= 128.0f; b2v /= 128.0f;
    out[0] = w1v + b1v + w2v + b2v;
    out[1] = w1v;
    out[2] = b1v;
    out[3] = w2v;
    out[4] = b2v;
  }
}

// ---------------------------------------------------------------------------
extern "C" void kernel_launch(void* const* d_in, const int* in_sizes, int n_in,
                              void* d_out, int out_size, void* d_ws, size_t ws_size,
                              hipStream_t stream) {
  const float* X  = (const float*)d_in[0];
  const float* W1 = (const float*)d_in[1];
  const float* b1 = (const float*)d_in[2];
  const float* W2 = (const float*)d_in[3];
  const float* b2 = (const float*)d_in[4];
  float* out = (float*)d_out;

  float* ws        = (float*)d_ws;
  float* hpre      = ws;                       // 131072
  float* lpart     = hpre + 131072;            // 2 * 131072
  float* g         = lpart + 262144;           // 131072 (stride 1024, zero-padded)
  float* xsq       = g + 131072;               // 128
  float* samp_part = xsq + 128;                // 256
  float* bwd_part  = samp_part + 256;          // 2048

  k_fc1<<<dim3(8, 32), 256, 0, stream>>>(X, W1, b1, hpre);
  k_fc2<<<dim3(8, 16, 2), 256, 0, stream>>>(hpre, W2, lpart);
  k_sample<<<B_N, 512, 0, stream>>>(X, hpre, lpart, b2, g, xsq, samp_part);
  k_bwd1<<<dim3(64, 16), 512, 0, stream>>>(g, W2, hpre, xsq, bwd_part);
  k_final<<<1, 512, 0, stream>>>(samp_part, bwd_part, out);
}

// Round 3
// 57.428 us; speedup vs baseline: 2.6937x; 1.1553x over previous
//
#include <hip/hip_runtime.h>
#include <hip/hip_bf16.h>
#include <stdint.h>
#include <math.h>

#define B_N 128
#define D_N 512
#define H_N 1024
#define C_N 1000
#define CP  1024   // padded row stride for logits/g
#define NPART 8    // fc2 K-split

// ---------------------------------------------------------------------------
// threefry2x32 (JAX-compatible, 20 rounds) -- verified bit-exact (R1 absmax 0)
// ---------------------------------------------------------------------------
__device__ __forceinline__ uint32_t rotl32(uint32_t v, int r) {
  return (v << r) | (v >> (32 - r));
}

__device__ __forceinline__ void threefry2x32(uint32_t k0, uint32_t k1,
                                             uint32_t x0, uint32_t x1,
                                             uint32_t &o0, uint32_t &o1) {
  uint32_t ks2 = k0 ^ k1 ^ 0x1BD11BDAu;
#define TF_R(r) { x0 += x1; x1 = rotl32(x1, r); x1 ^= x0; }
  x0 += k0; x1 += k1;
  TF_R(13) TF_R(15) TF_R(26) TF_R(6)
  x0 += k1; x1 += ks2 + 1u;
  TF_R(17) TF_R(29) TF_R(16) TF_R(24)
  x0 += ks2; x1 += k0 + 2u;
  TF_R(13) TF_R(15) TF_R(26) TF_R(6)
  x0 += k0; x1 += k1 + 3u;
  TF_R(17) TF_R(29) TF_R(16) TF_R(24)
  x0 += k1; x1 += ks2 + 4u;
  TF_R(13) TF_R(15) TF_R(26) TF_R(6)
  x0 += ks2; x1 += k0 + 5u;
#undef TF_R
  o0 = x0; o1 = x1;
}

__device__ __forceinline__ float gumbel_from_key(uint32_t k0, uint32_t k1, uint32_t i) {
  uint32_t o0, o1;
  threefry2x32(k0, k1, 0u, i, o0, o1);
  uint32_t bits = o0 ^ o1;
  uint32_t fb = (bits >> 9) | 0x3f800000u;
  float f = __uint_as_float(fb) - 1.0f;            // [0, 1)
  const float tiny = 1.1754943508222875e-38f;
  float u = fmaxf(tiny, f * (1.0f - tiny) + tiny); // JAX uniform(minval=tiny)
  return -logf(-logf(u));
}

// ---------------------------------------------------------------------------
// block reductions (512 threads = 8 waves)
// ---------------------------------------------------------------------------
__device__ __forceinline__ float block_sum512(float v, float* red) {
  #pragma unroll
  for (int o = 32; o; o >>= 1) v += __shfl_xor(v, o);
  __syncthreads();
  if ((threadIdx.x & 63) == 0) red[threadIdx.x >> 6] = v;
  __syncthreads();
  return red[0] + red[1] + red[2] + red[3] + red[4] + red[5] + red[6] + red[7];
}

__device__ __forceinline__ float block_max512(float v, float* red) {
  #pragma unroll
  for (int o = 32; o; o >>= 1) v = fmaxf(v, __shfl_xor(v, o));
  __syncthreads();
  if ((threadIdx.x & 63) == 0) red[threadIdx.x >> 6] = v;
  __syncthreads();
  float m = red[0];
  #pragma unroll
  for (int w = 1; w < 8; w++) m = fmaxf(m, red[w]);
  return m;
}

// ---------------------------------------------------------------------------
// K1: hpre[128][1024] = X @ W1 + b1.
// grid (8, 32), 512 thr: c-tile 128, 4 samples/block, 1 sample/thread.
// Double-buffered 16-wide W1 batches: prefetch i+1 issued before consuming i.
// ---------------------------------------------------------------------------
__global__ __launch_bounds__(512) void k_fc1(const float* __restrict__ X,
                                             const float* __restrict__ W1,
                                             const float* __restrict__ b1,
                                             float* __restrict__ hpre) {
  __shared__ float xs[4 * D_N];  // 8 KB
  int cbase = blockIdx.x * 128;
  int sbase = blockIdx.y * 4;
  int t = threadIdx.x;
  #pragma unroll
  for (int k = 0; k < 4; k++) {
    int idx = t + k * 512;            // 0..2047
    xs[idx] = X[(sbase + (idx >> 9)) * D_N + (idx & 511)];
  }
  __syncthreads();
  int c = cbase + (t & 127);
  const float* xp = &xs[(t >> 7) * D_N];
  const float* W1c = W1 + c;
  float wA[16], wB[16];
  #pragma unroll
  for (int i = 0; i < 16; i++) wA[i] = W1c[i * H_N];
  float acc = 0.f;
  for (int d0 = 0; d0 < D_N; d0 += 32) {
    #pragma unroll
    for (int i = 0; i < 16; i++) wB[i] = W1c[((d0 + 16 + i) & (D_N - 1)) * H_N];
    #pragma unroll
    for (int q = 0; q < 4; q++) {
      float4 xa = *reinterpret_cast<const float4*>(&xp[d0 + q * 4]);
      acc += xa.x * wA[q*4+0] + xa.y * wA[q*4+1] + xa.z * wA[q*4+2] + xa.w * wA[q*4+3];
    }
    #pragma unroll
    for (int i = 0; i < 16; i++) wA[i] = W1c[((d0 + 32 + i) & (D_N - 1)) * H_N];
    #pragma unroll
    for (int q = 0; q < 4; q++) {
      float4 xa = *reinterpret_cast<const float4*>(&xp[d0 + 16 + q * 4]);
      acc += xa.x * wB[q*4+0] + xa.y * wB[q*4+1] + xa.z * wB[q*4+2] + xa.w * wB[q*4+3];
    }
  }
  hpre[(sbase + (t >> 7)) * H_N + c] = acc + b1[c];
}

// ---------------------------------------------------------------------------
// K2: logits_part[kb][128][CP] partial over j in [kb*128, kb*128+128).
// grid (8, 16, NPART) = 1024 blocks, 256 thr -> 4 waves/SIMD.
// Double-buffered 16-wide W2 batches. b2 + part-sum applied in k_sample.
// ---------------------------------------------------------------------------
__global__ __launch_bounds__(256) void k_fc2(const float* __restrict__ hpre,
                                             const float* __restrict__ W2,
                                             float* __restrict__ logits_part) {
  __shared__ float hs[8 * 128];  // 4 KB
  int cbase = blockIdx.x * 128;
  int sbase = blockIdx.y * 8;
  int kb = blockIdx.z;           // 0..7
  int t = threadIdx.x;
  #pragma unroll
  for (int k = 0; k < 4; k++) {
    int idx = t + k * 256;            // 0..1023
    hs[idx] = fmaxf(hpre[(sbase + (idx >> 7)) * H_N + kb * 128 + (idx & 127)], 0.0f);
  }
  __syncthreads();
  int c = cbase + (t & 127);
  if (c >= C_N) return;              // no further barriers
  int sq = t >> 7;                   // 0,1 -> 4 samples each
  const float* hp0 = &hs[(sq * 4 + 0) * 128];
  const float* hp1 = &hs[(sq * 4 + 1) * 128];
  const float* hp2 = &hs[(sq * 4 + 2) * 128];
  const float* hp3 = &hs[(sq * 4 + 3) * 128];
  const float* W2c = W2 + (size_t)(kb * 128) * C_N + c;
  float wA[16], wB[16];
  #pragma unroll
  for (int i = 0; i < 16; i++) wA[i] = W2c[i * C_N];
  float a0 = 0.f, a1 = 0.f, a2 = 0.f, a3 = 0.f;
  for (int j0 = 0; j0 < 128; j0 += 32) {
    #pragma unroll
    for (int i = 0; i < 16; i++) wB[i] = W2c[((j0 + 16 + i) & 127) * C_N];
    #pragma unroll
    for (int q = 0; q < 4; q++) {
      float4 hA = *reinterpret_cast<const float4*>(&hp0[j0 + q * 4]);
      float4 hB = *reinterpret_cast<const float4*>(&hp1[j0 + q * 4]);
      float4 hC = *reinterpret_cast<const float4*>(&hp2[j0 + q * 4]);
      float4 hD = *reinterpret_cast<const float4*>(&hp3[j0 + q * 4]);
      a0 += hA.x * wA[q*4+0] + hA.y * wA[q*4+1] + hA.z * wA[q*4+2] + hA.w * wA[q*4+3];
      a1 += hB.x * wA[q*4+0] + hB.y * wA[q*4+1] + hB.z * wA[q*4+2] + hB.w * wA[q*4+3];
      a2 += hC.x * wA[q*4+0] + hC.y * wA[q*4+1] + hC.z * wA[q*4+2] + hC.w * wA[q*4+3];
      a3 += hD.x * wA[q*4+0] + hD.y * wA[q*4+1] + hD.z * wA[q*4+2] + hD.w * wA[q*4+3];
    }
    #pragma unroll
    for (int i = 0; i < 16; i++) wA[i] = W2c[((j0 + 32 + i) & 127) * C_N];
    #pragma unroll
    for (int q = 0; q < 4; q++) {
      float4 hA = *reinterpret_cast<const float4*>(&hp0[j0 + 16 + q * 4]);
      float4 hB = *reinterpret_cast<const float4*>(&hp1[j0 + 16 + q * 4]);
      float4 hC = *reinterpret_cast<const float4*>(&hp2[j0 + 16 + q * 4]);
      float4 hD = *reinterpret_cast<const float4*>(&hp3[j0 + 16 + q * 4]);
      a0 += hA.x * wB[q*4+0] + hA.y * wB[q*4+1] + hA.z * wB[q*4+2] + hA.w * wB[q*4+3];
      a1 += hB.x * wB[q*4+0] + hB.y * wB[q*4+1] + hB.z * wB[q*4+2] + hB.w * wB[q*4+3];
      a2 += hC.x * wB[q*4+0] + hC.y * wB[q*4+1] + hC.z * wB[q*4+2] + hC.w * wB[q*4+3];
      a3 += hD.x * wB[q*4+0] + hD.y * wB[q*4+1] + hD.z * wB[q*4+2] + hD.w * wB[q*4+3];
    }
  }
  float* lp = logits_part + (size_t)kb * (B_N * CP);
  int s0 = sbase + sq * 4;
  lp[(s0 + 0) * CP + c] = a0;
  lp[(s0 + 1) * CP + c] = a1;
  lp[(s0 + 2) * CP + c] = a2;
  lp[(s0 + 3) * CP + c] = a3;
}

// ---------------------------------------------------------------------------
// K3: sum NPART logit partials + b2; categorical sample; softmax grad g;
// W2/b2 trace partials. One block (512 thr) per sample.
// ---------------------------------------------------------------------------
__global__ __launch_bounds__(512) void k_sample(const float* __restrict__ X,
                                                const float* __restrict__ hpre,
                                                const float* __restrict__ logits_part,
                                                const float* __restrict__ b2,
                                                float* __restrict__ g,
                                                float* __restrict__ xsq_out,
                                                float* __restrict__ samp_part) {
  __shared__ float lg[C_N];
  __shared__ float red[8];
  __shared__ float redv[8];
  __shared__ int   redi[8];
  __shared__ uint32_t keys[2];
  int b = blockIdx.x;
  int t = threadIdx.x;

  {
    float sA = b2[t];
    float sB = (t + 512 < C_N) ? b2[t + 512] : 0.f;
    #pragma unroll
    for (int p = 0; p < NPART; p++) {
      const float* lp = logits_part + (size_t)p * (B_N * CP) + b * CP;
      sA += lp[t];
      if (t + 512 < C_N) sB += lp[t + 512];
    }
    lg[t] = sA;
    if (t + 512 < C_N) lg[t + 512] = sB;
  }
  if (t == 0) {
    uint32_t o0, o1;
    threefry2x32(0u, 42u, 0u, (uint32_t)b, o0, o1);
    keys[0] = o0; keys[1] = o1;
  }
  __syncthreads();
  uint32_t k0 = keys[0], k1 = keys[1];

  // gumbel-argmax over 1000 classes
  float bz = -INFINITY; int bi = 0x7fffffff;
  {
    float z0 = lg[t] + gumbel_from_key(k0, k1, (uint32_t)t);
    bz = z0; bi = t;
    if (t + 512 < C_N) {
      float z1 = lg[t + 512] + gumbel_from_key(k0, k1, (uint32_t)(t + 512));
      if (z1 > bz || (z1 == bz && (t + 512) < bi)) { bz = z1; bi = t + 512; }
    }
  }
  #pragma unroll
  for (int o = 32; o; o >>= 1) {
    float ov = __shfl_xor(bz, o);
    int   oi = __shfl_xor(bi, o);
    if (ov > bz || (ov == bz && oi < bi)) { bz = ov; bi = oi; }
  }
  if ((t & 63) == 0) { redv[t >> 6] = bz; redi[t >> 6] = bi; }
  __syncthreads();
  if (t == 0) {
    #pragma unroll
    for (int w = 1; w < 8; w++) {
      if (redv[w] > redv[0] || (redv[w] == redv[0] && redi[w] < redi[0])) {
        redv[0] = redv[w]; redi[0] = redi[w];
      }
    }
  }
  __syncthreads();
  int y = redi[0];

  // softmax
  float lm = lg[t];
  if (t + 512 < C_N) lm = fmaxf(lm, lg[t + 512]);
  float m = block_max512(lm, red);
  float ea = expf(lg[t] - m);
  float eb = (t + 512 < C_N) ? expf(lg[t + 512] - m) : 0.0f;
  float sum1 = block_sum512(ea + eb, red);
  float inv = 1.0f / sum1;

  float ga  = ea * inv - ((t == y) ? 1.0f : 0.0f);
  float gb2 = eb * inv - (((t + 512) == y) ? 1.0f : 0.0f);
  g[b * CP + t] = ga;
  g[b * CP + t + 512] = (t + 512 < C_N) ? gb2 : 0.0f;  // zero-pad cols 1000..1023
  float gn = ga * ga + ((t + 512 < C_N) ? gb2 * gb2 : 0.0f);
  float tnorm = block_sum512(gn, red);   // ||g||^2

  // ||h||^2
  float h0 = fmaxf(hpre[b * H_N + t], 0.0f);
  float h1 = fmaxf(hpre[b * H_N + t + 512], 0.0f);
  float hsq = block_sum512(h0 * h0 + h1 * h1, red);

  // ||x||^2
  float xv = (t < D_N) ? X[b * D_N + t] : 0.0f;
  float xsq = block_sum512(xv * xv, red);

  if (t == 0) {
    xsq_out[b] = xsq;
    samp_part[b * 2 + 0] = hsq * tnorm;  // W2 trace numerator
    samp_part[b * 2 + 1] = tnorm;        // b2 trace numerator
  }
}

// ---------------------------------------------------------------------------
// K4: wave-dot ghat = g . W2-rows (contiguous c axis), fused mask/square/trace.
// grid (64, 16) = 1024 blocks, 512 thr (32 waves/CU cap).
// ---------------------------------------------------------------------------
__global__ __launch_bounds__(512) void k_bwd1(const float* __restrict__ g,
                                              const float* __restrict__ W2,
                                              const float* __restrict__ hpre,
                                              const float* __restrict__ xsq,
                                              float* __restrict__ bwd_part) {
  __shared__ float gs[8 * 1024];  // 32 KB, zero-padded cols from k_sample
  __shared__ float xq[8];
  __shared__ float wred[8][2];
  int jb = blockIdx.x * 16;
  int sbase = blockIdx.y * 8;
  int t = threadIdx.x;
  #pragma unroll
  for (int k = 0; k < 16; k++) {
    int idx = t + k * 512;            // 0..8191
    gs[idx] = g[(sbase + (idx >> 10)) * CP + (idx & 1023)];
  }
  if (t < 8) xq[t] = xsq[sbase + t];
  __syncthreads();

  int w = t >> 6, lane = t & 63;
  int j0 = jb + w * 2, j1 = j0 + 1;
  float a0[8] = {0,0,0,0,0,0,0,0};
  float a1[8] = {0,0,0,0,0,0,0,0};
  const float* w2r0 = W2 + (size_t)j0 * C_N;
  const float* w2r1 = W2 + (size_t)j1 * C_N;
  #pragma unroll
  for (int it = 0; it < 4; it++) {
    int c0 = it * 256 + lane * 4;
    bool act = (c0 < C_N);            // only the it==3 tail can be inactive
    float4 wv0 = act ? *reinterpret_cast<const float4*>(w2r0 + c0)
                     : make_float4(0.f, 0.f, 0.f, 0.f);
    float4 wv1 = act ? *reinterpret_cast<const float4*>(w2r1 + c0)
                     : make_float4(0.f, 0.f, 0.f, 0.f);
    #pragma unroll
    for (int s = 0; s < 8; s++) {
      float4 gv = *reinterpret_cast<const float4*>(&gs[s * 1024 + c0]);
      a0[s] += wv0.x * gv.x + wv0.y * gv.y + wv0.z * gv.z + wv0.w * gv.w;
      a1[s] += wv1.x * gv.x + wv1.y * gv.y + wv1.z * gv.z + wv1.w * gv.w;
    }
  }
  #pragma unroll
  for (int off = 32; off; off >>= 1) {
    #pragma unroll
    for (int s = 0; s < 8; s++) {
      a0[s] += __shfl_xor(a0[s], off);
      a1[s] += __shfl_xor(a1[s], off);
    }
  }
  float cb = 0.f, cw = 0.f;
  #pragma unroll
  for (int s = 0; s < 8; s++) {
    float h0 = hpre[(sbase + s) * H_N + j0];
    float h1 = hpre[(sbase + s) * H_N + j1];
    float v0 = (h0 > 0.f) ? a0[s] : 0.f;
    float v1 = (h1 > 0.f) ? a1[s] : 0.f;
    float q = v0 * v0 + v1 * v1;
    cb += q;
    cw += xq[s] * q;
  }
  if (lane == 0) { wred[w][0] = cw; wred[w][1] = cb; }
  __syncthreads();
  if (t == 0) {
    float sw = 0.f, sb = 0.f;
    #pragma unroll
    for (int i = 0; i < 8; i++) { sw += wred[i][0]; sb += wred[i][1]; }
    int bid = blockIdx.y * 64 + blockIdx.x;
    bwd_part[bid * 2 + 0] = sw;   // W1 trace partial
    bwd_part[bid * 2 + 1] = sb;   // b1 trace partial
  }
}

// ---------------------------------------------------------------------------
// K5: deterministic final reduction of all partials -> out[5]
// ---------------------------------------------------------------------------
__global__ __launch_bounds__(512) void k_final(const float* __restrict__ samp_part,
                                               const float* __restrict__ bwd_part,
                                               float* __restrict__ out) {
  __shared__ float red[8];
  int t = threadIdx.x;
  float w1v = bwd_part[t * 2 + 0] + bwd_part[(t + 512) * 2 + 0];
  float b1v = bwd_part[t * 2 + 1] + bwd_part[(t + 512) * 2 + 1];
  float w2v = (t < B_N) ? samp_part[t * 2 + 0] : 0.f;
  float b2v = (t < B_N) ? samp_part[t * 2 + 1] : 0.f;
  w1v = block_sum512(w1v, red);
  b1v = block_sum512(b1v, red);
  w2v = block_sum512(w2v, red);
  b2v = block_sum512(b2v, red);
  if (t == 0) {
    w1v /= 128.0f; b1v /= 128.0f; w2v /= 128.0f; b2v /= 128.0f;
    out[0] = w1v + b1v + w2v + b2v;
    out[1] = w1v;
    out[2] = b1v;
    out[3] = w2v;
    out[4] = b2v;
  }
}

// ---------------------------------------------------------------------------
extern "C" void kernel_launch(void* const* d_in, const int* in_sizes, int n_in,
                              void* d_out, int out_size, void* d_ws, size_t ws_size,
                              hipStream_t stream) {
  const float* X  = (const float*)d_in[0];
  const float* W1 = (const float*)d_in[1];
  const float* b1 = (const float*)d_in[2];
  const float* W2 = (const float*)d_in[3];
  const float* b2 = (const float*)d_in[4];
  float* out = (float*)d_out;

  float* ws        = (float*)d_ws;
  float* hpre      = ws;                       // 131072
  float* lpart     = hpre + 131072;            // NPART * 131072
  float* g         = lpart + NPART * 131072;   // 131072 (stride 1024, zero-padded)
  float* xsq       = g + 131072;               // 128
  float* samp_part = xsq + 128;                // 256
  float* bwd_part  = samp_part + 256;          // 2048

  k_fc1<<<dim3(8, 32), 512, 0, stream>>>(X, W1, b1, hpre);
  k_fc2<<<dim3(8, 16, NPART), 256, 0, stream>>>(hpre, W2, lpart);
  k_sample<<<B_N, 512, 0, stream>>>(X, hpre, lpart, b2, g, xsq, samp_part);
  k_bwd1<<<dim3(64, 16), 512, 0, stream>>>(g, W2, hpre, xsq, bwd_part);
  k_final<<<1, 512, 0, stream>>>(samp_part, bwd_part, out);
}